// Round 6
// baseline (445.534 us; speedup 1.0000x reference)
//
#include <hip/hip_runtime.h>
#include <hip/hip_fp16.h>
#include <math.h>

#define NND 50000
#define NE  800000
#define HID 128
#define NGR 32
#define NLAYER 4
#define NBK 196                    // coarse buckets (dst>>8), 49999>>8 = 195
#define NBLK 831                   // CSR edge blocks (1024 items each)
#define NITEM (NE + NND)           // 850000 (edges + self-loops)

typedef _Float16 half8 __attribute__((ext_vector_type(8)));
typedef _Float16 half2v __attribute__((ext_vector_type(2)));
typedef float float4v __attribute__((ext_vector_type(4)));

static __device__ __forceinline__ unsigned fenc(float f){
  unsigned u = __float_as_uint(f);
  return (u & 0x80000000u) ? ~u : (u | 0x80000000u);
}
static __device__ __forceinline__ float fdec(unsigned u){
  return __uint_as_float((u & 0x80000000u) ? (u & 0x7fffffffu) : ~u);
}

// ============ CSR build: two-level counting sort, ZERO global atomics ============
// (round-4 win: replaced 850k device-scope atomics that were IC-RMW-throughput-bound)

__global__ __launch_bounds__(256) void k_count(const float* __restrict__ Ws, const float* __restrict__ skip_W,
    _Float16* __restrict__ wth, const int* __restrict__ ei, unsigned short* __restrict__ cnts)
{
  if (blockIdx.x < 5) {
    int m = blockIdx.x;           // 0..3 layers, 4 = skip_W
    const float* src = (m < 4) ? (Ws + (size_t)m * 16384) : skip_W;
    _Float16* oh = wth + (size_t)m * 16384;
    for (int i = threadIdx.x; i < 16384; i += 256){
      int c = i >> 7, k = i & 127;
      oh[i] = (_Float16)src[k * 128 + c];
    }
    return;
  }
  int blk = blockIdx.x - 5;
  __shared__ unsigned h[NBK];
  for (int i = threadIdx.x; i < NBK; i += 256) h[i] = 0;
  __syncthreads();
  int e0 = blk * 1024 + threadIdx.x;
#pragma unroll
  for (int i = 0; i < 4; ++i) {
    int e = e0 + i * 256;
    if (e < NITEM) {
      int d = (e < NE) ? ei[NE + e] : (e - NE);
      atomicAdd(&h[d >> 8], 1u);
    }
  }
  __syncthreads();
  for (int i = threadIdx.x; i < NBK; i += 256)
    cnts[(size_t)i * NBLK + blk] = (unsigned short)h[i];
}

__global__ __launch_bounds__(256) void k_scan1(const unsigned short* __restrict__ cnts,
    unsigned* __restrict__ offs, unsigned* __restrict__ totals)
{
  int b = blockIdx.x;
  int t = threadIdx.x;
  int lane = t & 63, wid = t >> 6;
  unsigned v[4];
  int i0 = t * 4;
#pragma unroll
  for (int k = 0; k < 4; ++k) {
    int i = i0 + k;
    v[k] = (i < NBLK) ? (unsigned)cnts[(size_t)b * NBLK + i] : 0u;
  }
  unsigned cs = v[0] + v[1] + v[2] + v[3];
  unsigned incl = cs;
#pragma unroll
  for (int o = 1; o < 64; o <<= 1) { unsigned u = __shfl_up(incl, o); if (lane >= o) incl += u; }
  __shared__ unsigned wsum[4];
  if (lane == 63) wsum[wid] = incl;
  __syncthreads();
  unsigned wbase = 0;
#pragma unroll
  for (int k = 0; k < 4; ++k) if (k < wid) wbase += wsum[k];
  unsigned run = wbase + incl - cs;
#pragma unroll
  for (int k = 0; k < 4; ++k) {
    int i = i0 + k;
    if (i < NBLK) offs[(size_t)b * NBLK + i] = run;
    run += v[k];
  }
  if (t == 255) totals[b] = wbase + incl;
}

__global__ __launch_bounds__(256) void k_scan2(const unsigned* __restrict__ totals, unsigned* __restrict__ base)
{
  int t = threadIdx.x;
  int lane = t & 63, wid = t >> 6;
  unsigned v = (t < NBK) ? totals[t] : 0u;
  unsigned incl = v;
#pragma unroll
  for (int o = 1; o < 64; o <<= 1) { unsigned u = __shfl_up(incl, o); if (lane >= o) incl += u; }
  __shared__ unsigned wsum[4];
  if (lane == 63) wsum[wid] = incl;
  __syncthreads();
  unsigned wbase = 0;
#pragma unroll
  for (int k = 0; k < 4; ++k) if (k < wid) wbase += wsum[k];
  if (t < NBK) base[t] = wbase + incl - v;
  if (t == 255) base[NBK] = wbase + incl;   // = NITEM
}

__global__ __launch_bounds__(256) void k_scatter(const int* __restrict__ ei, const unsigned* __restrict__ offs,
    const unsigned* __restrict__ base, unsigned* __restrict__ ebuf)
{
  int blk = blockIdx.x;
  __shared__ unsigned cur[NBK];
  for (int i = threadIdx.x; i < NBK; i += 256)
    cur[i] = base[i] + offs[(size_t)i * NBLK + blk];
  __syncthreads();
  int e0 = blk * 1024 + threadIdx.x;
#pragma unroll
  for (int i = 0; i < 4; ++i) {
    int e = e0 + i * 256;
    if (e < NITEM) {
      int s, d;
      if (e < NE) { s = ei[e]; d = ei[NE + e]; } else { s = e - NE; d = e - NE; }
      unsigned pos = atomicAdd(&cur[d >> 8], 1u);        // LDS atomic
      ebuf[pos] = ((unsigned)d << 16) | (unsigned)s;     // both < 65536
    }
  }
}

__global__ __launch_bounds__(256) void k_fine(const unsigned* __restrict__ ebuf, const unsigned* __restrict__ base,
    unsigned* __restrict__ starts, unsigned short* __restrict__ srcs, int N)
{
  int b = blockIdx.x;
  int t = threadIdx.x;
  unsigned lo = base[b], hi = base[b + 1];
  int d0 = b << 8;
  __shared__ unsigned h[256], st[256], wsum[4];
  h[t] = 0;
  __syncthreads();
  for (unsigned i = lo + t; i < hi; i += 256)
    atomicAdd(&h[(ebuf[i] >> 16) - d0], 1u);
  __syncthreads();
  unsigned v = h[t];
  int lane = t & 63, wid = t >> 6;
  unsigned incl = v;
#pragma unroll
  for (int o = 1; o < 64; o <<= 1) { unsigned u = __shfl_up(incl, o); if (lane >= o) incl += u; }
  if (lane == 63) wsum[wid] = incl;
  __syncthreads();
  unsigned wbase = 0;
#pragma unroll
  for (int k = 0; k < 4; ++k) if (k < wid) wbase += wsum[k];
  unsigned excl = wbase + incl - v;
  st[t] = excl;
  int dst = d0 + t;
  if (dst < N) starts[dst] = lo + excl;
  if (b == NBK - 1 && t == 0) starts[N] = hi;
  h[t] = 0;
  __syncthreads();
  for (unsigned i = lo + t; i < hi; i += 256) {
    unsigned w = ebuf[i];
    unsigned dl = (w >> 16) - d0;
    unsigned r = atomicAdd(&h[dl], 1u);
    srcs[lo + st[dl] + r] = (unsigned short)(w & 0xFFFFu);
  }
}

// ======== Round-5: fused skip+layer0 GEMM — one pass over x, two B matrices ========
__global__ __launch_bounds__(256) void k_gemm2(const float* __restrict__ x,
    const _Float16* __restrict__ wt0, const _Float16* __restrict__ wts,
    const float* __restrict__ skip_b,
    const float* __restrict__ a_s, const float* __restrict__ a_d,
    float* __restrict__ skip, _Float16* __restrict__ hW,
    float* __restrict__ es, float* __restrict__ ed, int N)
{
  int tid = threadIdx.x;
  int w  = tid >> 6;
  int l  = tid & 63;
  int ln = l & 15;
  int q  = l >> 4;
  int row0 = blockIdx.x * 64;
  int row = row0 + w * 16 + ln;
  bool rok = row < N;
  const float4* Arow = (const float4*)(x + (size_t)(rok ? row : 0) * 128);

  half8 af[4];
#pragma unroll
  for (int k32 = 0; k32 < 4; ++k32) {
    int f4 = k32 * 8 + q * 2;
    float4 a0 = make_float4(0.f,0.f,0.f,0.f), a1 = a0;
    if (rok) { a0 = Arow[f4]; a1 = Arow[f4 + 1]; }
    half8 h = {(_Float16)a0.x, (_Float16)a0.y, (_Float16)a0.z, (_Float16)a0.w,
               (_Float16)a1.x, (_Float16)a1.y, (_Float16)a1.z, (_Float16)a1.w};
    af[k32] = h;
  }

  float4v acc0[8], accs[8];
#pragma unroll
  for (int t = 0; t < 8; ++t) { acc0[t] = (float4v){0,0,0,0}; accs[t] = (float4v){0,0,0,0}; }

#pragma unroll
  for (int k32 = 0; k32 < 4; ++k32) {
    int kk = k32 * 32 + q * 8;
#pragma unroll
    for (int t = 0; t < 8; ++t) {
      half8 b0 = *(const half8*)(&wt0[(size_t)(t * 16 + ln) * 128 + kk]);
      acc0[t] = __builtin_amdgcn_mfma_f32_16x16x32_f16(af[k32], b0, acc0[t], 0, 0, 0);
      half8 bs = *(const half8*)(&wts[(size_t)(t * 16 + ln) * 128 + kk]);
      accs[t] = __builtin_amdgcn_mfma_f32_16x16x32_f16(af[k32], bs, accs[t], 0, 0, 0);
    }
  }

  float bb[8];
#pragma unroll
  for (int t = 0; t < 8; ++t) bb[t] = skip_b[t * 16 + ln];
#pragma unroll
  for (int t = 0; t < 8; ++t) {
#pragma unroll
    for (int r = 0; r < 4; ++r) {
      int gr = row0 + w * 16 + q * 4 + r;
      if (gr < N) {
        int col = t * 16 + ln;
        skip[(size_t)gr * 128 + col] = accs[t][r] + bb[t];
        hW[(size_t)gr * 128 + col] = (_Float16)acc0[t][r];
      }
    }
  }
  // es/ed from layer-0 acc
  {
    float asv[8], adv[8];
#pragma unroll
    for (int t = 0; t < 8; ++t) { asv[t] = a_s[t * 16 + ln]; adv[t] = a_d[t * 16 + ln]; }
    float ps[4], pd[4];
#pragma unroll
    for (int r = 0; r < 4; ++r) {
      float s_ = 0.f, d_ = 0.f;
#pragma unroll
      for (int t = 0; t < 8; ++t) { s_ += acc0[t][r] * asv[t]; d_ += acc0[t][r] * adv[t]; }
      ps[r] = s_; pd[r] = d_;
    }
#pragma unroll
    for (int o = 1; o < 16; o <<= 1) {
#pragma unroll
      for (int r = 0; r < 4; ++r) { ps[r] += __shfl_xor(ps[r], o); pd[r] += __shfl_xor(pd[r], o); }
    }
    if (ln == 0) {
#pragma unroll
      for (int r = 0; r < 4; ++r) {
        int gr = row0 + w * 16 + q * 4 + r;
        if (gr < N) { es[gr] = ps[r]; ed[gr] = pd[r]; }
      }
    }
  }
}

// ======== Round-5: layers 1-3 GEMM reads fp16 A (hA mirror from edge_agg) ========
// Bitwise-identical to the old fp32-read-then-cast path: hA holds the RNE fp16 cast
// of the exact fp32 value the old path would have loaded and cast.
__global__ __launch_bounds__(256) void gemm_h(const _Float16* __restrict__ A,
    const _Float16* __restrict__ wt,
    const float* __restrict__ a_s, const float* __restrict__ a_d,
    _Float16* __restrict__ outH, float* __restrict__ es, float* __restrict__ ed, int N)
{
  int tid = threadIdx.x;
  int w  = tid >> 6;
  int l  = tid & 63;
  int ln = l & 15;
  int q  = l >> 4;
  int row0 = blockIdx.x * 64;
  int row = row0 + w * 16 + ln;
  bool rok = row < N;
  const _Float16* Arow = A + (size_t)(rok ? row : 0) * 128;

  half8 hz = {(_Float16)0,(_Float16)0,(_Float16)0,(_Float16)0,
              (_Float16)0,(_Float16)0,(_Float16)0,(_Float16)0};
  half8 af[4];
#pragma unroll
  for (int k32 = 0; k32 < 4; ++k32)
    af[k32] = rok ? *(const half8*)(Arow + k32 * 32 + q * 8) : hz;

  float4v acc[8];
#pragma unroll
  for (int t = 0; t < 8; ++t) acc[t] = (float4v){0,0,0,0};

#pragma unroll
  for (int k32 = 0; k32 < 4; ++k32) {
    int kk = k32 * 32 + q * 8;
#pragma unroll
    for (int t = 0; t < 8; ++t) {
      half8 bv = *(const half8*)(&wt[(size_t)(t * 16 + ln) * 128 + kk]);
      acc[t] = __builtin_amdgcn_mfma_f32_16x16x32_f16(af[k32], bv, acc[t], 0, 0, 0);
    }
  }

#pragma unroll
  for (int t = 0; t < 8; ++t) {
#pragma unroll
    for (int r = 0; r < 4; ++r) {
      int gr = row0 + w * 16 + q * 4 + r;
      if (gr < N) outH[(size_t)gr * 128 + t * 16 + ln] = (_Float16)acc[t][r];
    }
  }
  {
    float asv[8], adv[8];
#pragma unroll
    for (int t = 0; t < 8; ++t) { asv[t] = a_s[t * 16 + ln]; adv[t] = a_d[t * 16 + ln]; }
    float ps[4], pd[4];
#pragma unroll
    for (int r = 0; r < 4; ++r) {
      float s_ = 0.f, d_ = 0.f;
#pragma unroll
      for (int t = 0; t < 8; ++t) { s_ += acc[t][r] * asv[t]; d_ += acc[t][r] * adv[t]; }
      ps[r] = s_; pd[r] = d_;
    }
#pragma unroll
    for (int o = 1; o < 16; o <<= 1) {
#pragma unroll
      for (int r = 0; r < 4; ++r) { ps[r] += __shfl_xor(ps[r], o); pd[r] += __shfl_xor(pd[r], o); }
    }
    if (ln == 0) {
#pragma unroll
      for (int r = 0; r < 4; ++r) {
        int gr = row0 + w * 16 + q * 4 + r;
        if (gr < N) { es[gr] = ps[r]; ed[gr] = pd[r]; }
      }
    }
  }
}

// ---------------- fused edge softmax + aggregate + bias + LN + ELU + residual ----------------
// Round-4 (kept): dense CSR (starts + packed u16 srcs).
// Round-3 (kept): epilogue spread over 64 lanes, ELU via __expf-1.
// Round-0 (kept): PF=4 preload + shfl broadcast of (alpha, s).
// Round-5: epilogue also emits fp16 mirror hA (A-input of next layer's GEMM).
__global__ __launch_bounds__(256) void edge_agg(
    const __half* __restrict__ hW, const float* __restrict__ es, const float* __restrict__ ed,
    const unsigned* __restrict__ starts, const unsigned short* __restrict__ srcs,
    const float* __restrict__ gb, const float* __restrict__ lg, const float* __restrict__ lb,
    const float* __restrict__ resid, float* __restrict__ hout, _Float16* __restrict__ hA,
    int do_elu, int N)
{
  __shared__ uint2 s_as[4][64];
  int wid = threadIdx.x >> 6;
  int lane = threadIdx.x & 63;
  int sub = lane >> 4;
  int sl  = lane & 15;
  int dst = blockIdx.x * 4 + wid;
  if (dst >= N) return;

  unsigned st0 = starts[dst];
  int deg = (int)(starts[dst + 1] - st0);
  float edv = ed[dst];

  float acc[8];
#pragma unroll
  for (int k = 0; k < 8; ++k) acc[k] = 0.f;
  const uint4* h4 = (const uint4*)hW;

  if (deg <= 64) {
    int s = 0;
    if (lane < deg) s = srcs[st0 + lane];
    const int PF = 4;
    uint4 qd_pre[PF];
#pragma unroll
    for (int i = 0; i < PF; ++i) {
      int idx = (i << 2) | sub;
      int sv = __shfl(s, idx);
      qd_pre[i] = make_uint4(0u, 0u, 0u, 0u);
      if (idx < deg) qd_pre[i] = h4[(size_t)sv * 16 + sl];
    }
    float x = -1e30f;
    if (lane < deg) {
      float xx = es[s] + edv;
      x = xx > 0.f ? xx : 0.2f * xx;
    }
    float m = x;
#pragma unroll
    for (int o = 32; o; o >>= 1) m = fmaxf(m, __shfl_xor(m, o));
    float p_ = (lane < deg) ? __expf(x - m) : 0.f;
    float z = p_;
#pragma unroll
    for (int o = 32; o; o >>= 1) z += __shfl_xor(z, o);
    float a_l = p_ / z;

    int iters = (deg + 3) >> 2;
#pragma unroll
    for (int i = 0; i < PF; ++i) {
      int idx = (i << 2) | sub;
      float a = __shfl(a_l, idx);
      uint4 qd = qd_pre[i];
      float2 f0 = __half22float2(*(__half2*)&qd.x);
      float2 f1 = __half22float2(*(__half2*)&qd.y);
      float2 f2 = __half22float2(*(__half2*)&qd.z);
      float2 f3 = __half22float2(*(__half2*)&qd.w);
      acc[0] += a * f0.x; acc[1] += a * f0.y;
      acc[2] += a * f1.x; acc[3] += a * f1.y;
      acc[4] += a * f2.x; acc[5] += a * f2.y;
      acc[6] += a * f3.x; acc[7] += a * f3.y;
    }
    for (int i = PF; i < iters; ++i) {
      int idx = (i << 2) | sub;
      float a = __shfl(a_l, idx);
      int sv = __shfl(s, idx);
      if (idx < deg) {
        uint4 qd = h4[(size_t)sv * 16 + sl];
        float2 f0 = __half22float2(*(__half2*)&qd.x);
        float2 f1 = __half22float2(*(__half2*)&qd.y);
        float2 f2 = __half22float2(*(__half2*)&qd.z);
        float2 f3 = __half22float2(*(__half2*)&qd.w);
        acc[0] += a * f0.x; acc[1] += a * f0.y;
        acc[2] += a * f1.x; acc[3] += a * f1.y;
        acc[4] += a * f2.x; acc[5] += a * f2.y;
        acc[6] += a * f3.x; acc[7] += a * f3.y;
      }
    }
  } else {
    float m = -1e30f;
    for (int j = lane; j < deg; j += 64) {
      float x = es[srcs[st0 + j]] + edv;
      x = x > 0.f ? x : 0.2f * x;
      m = fmaxf(m, x);
    }
#pragma unroll
    for (int o = 32; o; o >>= 1) m = fmaxf(m, __shfl_xor(m, o));
    float z = 0.f;
    for (int j = lane; j < deg; j += 64) {
      float x = es[srcs[st0 + j]] + edv;
      x = x > 0.f ? x : 0.2f * x;
      z += __expf(x - m);
    }
#pragma unroll
    for (int o = 32; o; o >>= 1) z += __shfl_xor(z, o);
    float inv_z = 1.0f / z;
    for (int c0 = 0; c0 < deg; c0 += 64) {
      int j = c0 + lane;
      int cnt = min(64, deg - c0);
      int s = 0; float p_ = 0.f;
      if (j < deg) {
        s = srcs[st0 + j];
        float x = es[s] + edv;
        x = x > 0.f ? x : 0.2f * x;
        p_ = __expf(x - m) * inv_z;
      }
      s_as[wid][lane] = make_uint2(__float_as_uint(p_), (unsigned)s);
      int iters = (cnt + 3) >> 2;
      for (int i = 0; i < iters; ++i) {
        int idx = (i << 2) | sub;
        bool valid = idx < cnt;
        uint2 av = s_as[wid][valid ? idx : 0];
        float a = valid ? __uint_as_float(av.x) : 0.f;
        uint4 qd = h4[(size_t)av.y * 16 + sl];
        float2 f0 = __half22float2(*(__half2*)&qd.x);
        float2 f1 = __half22float2(*(__half2*)&qd.y);
        float2 f2 = __half22float2(*(__half2*)&qd.z);
        float2 f3 = __half22float2(*(__half2*)&qd.w);
        acc[0] += a * f0.x; acc[1] += a * f0.y;
        acc[2] += a * f1.x; acc[3] += a * f1.y;
        acc[4] += a * f2.x; acc[5] += a * f2.y;
        acc[6] += a * f3.x; acc[7] += a * f3.y;
      }
    }
  }

#pragma unroll
  for (int k = 0; k < 8; ++k) {
    acc[k] += __shfl_xor(acc[k], 16);
    acc[k] += __shfl_xor(acc[k], 32);
  }

  float4 g0 = ((const float4*)gb)[sl * 2];
  float4 g1 = ((const float4*)gb)[sl * 2 + 1];
  float v[8];
  v[0] = acc[0] + g0.x; v[1] = acc[1] + g0.y; v[2] = acc[2] + g0.z; v[3] = acc[3] + g0.w;
  v[4] = acc[4] + g1.x; v[5] = acc[5] + g1.y; v[6] = acc[6] + g1.z; v[7] = acc[7] + g1.w;
  float s1 = 0.f, s2 = 0.f;
#pragma unroll
  for (int k = 0; k < 8; ++k) { s1 += v[k]; s2 += v[k] * v[k]; }
#pragma unroll
  for (int o = 8; o; o >>= 1) { s1 += __shfl_xor(s1, o); s2 += __shfl_xor(s2, o); }
  float mu = s1 * (1.f / 128.f);
  float var = s2 * (1.f / 128.f) - mu * mu;
  float rstd = rsqrtf(var + 1e-5f);

  // all 64 lanes: 2 cols each (col = 8*sl + 2*sub)
  float va = sub == 0 ? v[0] : (sub == 1 ? v[2] : (sub == 2 ? v[4] : v[6]));
  float vb = sub == 0 ? v[1] : (sub == 1 ? v[3] : (sub == 2 ? v[5] : v[7]));
  int col = sl * 8 + sub * 2;
  float2 Lv = *(const float2*)(lg + col);
  float2 Bv = *(const float2*)(lb + col);
  float2 Rv = *(const float2*)(resid + (long)dst * 128 + col);
  float t0 = (va - mu) * rstd * Lv.x + Bv.x;
  float t1 = (vb - mu) * rstd * Lv.y + Bv.y;
  if (do_elu) {
    t0 = t0 > 0.f ? t0 : __expf(t0) - 1.f;
    t1 = t1 > 0.f ? t1 : __expf(t1) - 1.f;
  }
  float y0 = t0 + Rv.x, y1 = t1 + Rv.y;
  *(float2*)(hout + (long)dst * 128 + col) = make_float2(y0, y1);
  if (hA) {
    half2v hv = {(_Float16)y0, (_Float16)y1};
    *(half2v*)(hA + (long)dst * 128 + col) = hv;
  }
}

// ---------------- pooling (mean + max per graph) ----------------
__global__ __launch_bounds__(128) void k_pool(const float* __restrict__ h, const int* __restrict__ batch,
    float* __restrict__ gsum, unsigned* __restrict__ gmax, int* __restrict__ gcnt, int N)
{
  int n0 = blockIdx.x * 64;
  int c = threadIdx.x;
  int cur = -1; float ls = 0.f, lm = -1e30f; int lc = 0;
  for (int i = 0; i < 64; ++i) {
    int n = n0 + i;
    if (n >= N) break;
    int g = batch[n];
    if (g != cur) {
      if (lc > 0) {
        atomicAdd(&gsum[cur * HID + c], ls);
        atomicMax(&gmax[cur * HID + c], fenc(lm));
        if (c == 0) atomicAdd(&gcnt[cur], lc);
      }
      cur = g; ls = 0.f; lm = -1e30f; lc = 0;
    }
    float v = h[(long)n * HID + c];
    ls += v; lm = fmaxf(lm, v); lc++;
  }
  if (lc > 0) {
    atomicAdd(&gsum[cur * HID + c], ls);
    atomicMax(&gmax[cur * HID + c], fenc(lm));
    if (c == 0) atomicAdd(&gcnt[cur], lc);
  }
}

// ---------------- final MLP: one block per graph ----------------
__global__ __launch_bounds__(128) void k_mlp(const float* __restrict__ gsum,
    const unsigned* __restrict__ gmax, const int* __restrict__ gcnt,
    const float* __restrict__ W1, const float* __restrict__ b1,
    const float* __restrict__ W2, const float* __restrict__ b2,
    const float* __restrict__ W3, const float* __restrict__ b3,
    float* __restrict__ out)
{
  int g = blockIdx.x;
  int c = threadIdx.x;
  __shared__ float G[256];
  __shared__ float O1[128];
  __shared__ float O2[64];
  float inv = 1.0f / fmaxf((float)gcnt[g], 1.0f);
  G[c]       = gsum[g * HID + c] * inv;
  G[128 + c] = fdec(gmax[g * HID + c]);
  __syncthreads();
  {
    float acc = 0.f;
#pragma unroll 8
    for (int k = 0; k < 256; ++k) acc += G[k] * W1[k * 128 + c];
    float v = acc + b1[c];
    O1[c] = v > 0.f ? v : 0.f;
  }
  __syncthreads();
  if (c < 64) {
    float acc = 0.f;
#pragma unroll 8
    for (int k = 0; k < 128; ++k) acc += O1[k] * W2[k * 64 + c];
    float v = acc + b2[c];
    O2[c] = v > 0.f ? v : 0.f;
  }
  __syncthreads();
  if (c < 4) {
    float acc = 0.f;
#pragma unroll 8
    for (int k = 0; k < 64; ++k) acc += O2[k] * W3[k * 4 + c];
    out[g * 4 + c] = acc + b3[c];
  }
}

extern "C" void kernel_launch(void* const* d_in, const int* in_sizes, int n_in,
                              void* d_out, int out_size, void* d_ws, size_t ws_size,
                              hipStream_t stream) {
  const float* x      = (const float*)d_in[0];
  const int*   ei     = (const int*)d_in[1];
  const int*   batch  = (const int*)d_in[2];
  const float* Ws     = (const float*)d_in[3];
  const float* a_src  = (const float*)d_in[4];
  const float* a_dst  = (const float*)d_in[5];
  const float* gat_b  = (const float*)d_in[6];
  const float* ln_g   = (const float*)d_in[7];
  const float* ln_b   = (const float*)d_in[8];
  const float* skip_W = (const float*)d_in[9];
  const float* skip_b = (const float*)d_in[10];
  const float* W1     = (const float*)d_in[11];
  const float* b1     = (const float*)d_in[12];
  const float* W2     = (const float*)d_in[13];
  const float* b2     = (const float*)d_in[14];
  const float* W3     = (const float*)d_in[15];
  const float* b3     = (const float*)d_in[16];
  float* out = (float*)d_out;

  const int N = NND;

  char* p = (char*)d_ws;
  auto alloc = [&](size_t bytes) -> void* {
    void* r = (void*)p;
    p += (bytes + 255) & ~(size_t)255;
    return r;
  };
  float*  skip  = (float*)alloc(sizeof(float) * (size_t)N * HID);
  float*  hcur  = (float*)alloc(sizeof(float) * (size_t)N * HID);
  _Float16* hW  = (_Float16*)alloc(sizeof(_Float16) * (size_t)N * HID);
  _Float16* hA  = (_Float16*)alloc(sizeof(_Float16) * (size_t)N * HID);
  float*  es    = (float*)alloc(sizeof(float) * N);
  float*  ed    = (float*)alloc(sizeof(float) * N);
  _Float16* wth = (_Float16*)alloc(sizeof(_Float16) * 5 * 16384);
  unsigned short* cnts = (unsigned short*)alloc(sizeof(unsigned short) * (size_t)NBK * NBLK);
  unsigned* offs   = (unsigned*)alloc(sizeof(unsigned) * (size_t)NBK * NBLK);
  unsigned* totals = (unsigned*)alloc(sizeof(unsigned) * NBK);
  unsigned* base   = (unsigned*)alloc(sizeof(unsigned) * (NBK + 1));
  unsigned* ebuf   = (unsigned*)alloc(sizeof(unsigned) * (size_t)NITEM);
  unsigned* starts = (unsigned*)alloc(sizeof(unsigned) * (N + 1));
  unsigned short* srcs = (unsigned short*)alloc(sizeof(unsigned short) * (size_t)NITEM);
  char*   zbeg  = p;
  float*  gsum  = (float*)alloc(sizeof(float) * NGR * HID);
  unsigned* gmax = (unsigned*)alloc(sizeof(unsigned) * NGR * HID);
  int*    gcnt  = (int*)alloc(sizeof(int) * NGR);
  size_t zlen = (size_t)(p - zbeg);

  int gblocks = (N + 63) / 64;            // 782

  // ---- CSR build (atomic-free counting sort) ∪ weight convert ----
  k_count  <<<5 + NBLK, 256, 0, stream>>>(Ws, skip_W, wth, ei, cnts);
  k_scan1  <<<NBK, 256, 0, stream>>>(cnts, offs, totals);
  k_scan2  <<<1, 256, 0, stream>>>(totals, base);
  k_scatter<<<NBLK, 256, 0, stream>>>(ei, offs, base, ebuf);
  k_fine   <<<NBK, 256, 0, stream>>>(ebuf, base, starts, srcs, N);

  // ---- fused skip + layer-0 GEMM (one pass over x) ----
  k_gemm2<<<gblocks, 256, 0, stream>>>(x, wth, wth + 4 * 16384, skip_b, a_src, a_dst,
                                       skip, hW, es, ed, N);
  edge_agg<<<(N + 3) / 4, 256, 0, stream>>>((const __half*)hW, es, ed, starts, srcs,
                                 gat_b, ln_g, ln_b, skip, hcur, hA, 1, N);

  // ---- layers 1..3 (fp16 A path) ----
  for (int l = 1; l < NLAYER; ++l) {
    gemm_h<<<gblocks, 256, 0, stream>>>(hA, wth + (size_t)l * 16384,
                                        a_src + l * HID, a_dst + l * HID,
                                        hW, es, ed, N);
    edge_agg<<<(N + 3) / 4, 256, 0, stream>>>((const __half*)hW, es, ed, starts, srcs,
                                   gat_b + l * HID, ln_g + l * HID, ln_b + l * HID,
                                   hcur, hcur, (l < NLAYER - 1) ? hA : (_Float16*)nullptr,
                                   (l < NLAYER - 1) ? 1 : 0, N);
  }

  // ---- pooling + MLP ----
  hipMemsetAsync(zbeg, 0, zlen, stream);
  k_pool<<<(N + 63) / 64, 128, 0, stream>>>(hcur, batch, gsum, gmax, gcnt, N);
  k_mlp<<<NGR, 128, 0, stream>>>(gsum, gmax, gcnt, W1, b1, W2, b2, W3, b3, out);
}

// Round 7
// 382.157 us; speedup vs baseline: 1.1658x; 1.1658x over previous
//
#include <hip/hip_runtime.h>
#include <hip/hip_fp16.h>
#include <math.h>

#define NND 50000
#define NE  800000
#define HID 128
#define NGR 32
#define NLAYER 4
#define NBK 196                    // coarse buckets (dst>>8), 49999>>8 = 195
#define NBLK 831                   // CSR edge blocks (1024 items each)
#define NITEM (NE + NND)           // 850000 (edges + self-loops)

typedef _Float16 half8 __attribute__((ext_vector_type(8)));
typedef _Float16 half2v __attribute__((ext_vector_type(2)));
typedef float float4v __attribute__((ext_vector_type(4)));

static __device__ __forceinline__ unsigned fenc(float f){
  unsigned u = __float_as_uint(f);
  return (u & 0x80000000u) ? ~u : (u | 0x80000000u);
}
static __device__ __forceinline__ float fdec(unsigned u){
  return __uint_as_float((u & 0x80000000u) ? (u & 0x7fffffffu) : ~u);
}

// ============ CSR build: two-level counting sort, ZERO global atomics ============
// (round-4 win: replaced 850k device-scope atomics that were IC-RMW-throughput-bound)

__global__ __launch_bounds__(256) void k_count(const float* __restrict__ Ws, const float* __restrict__ skip_W,
    _Float16* __restrict__ wth, const int* __restrict__ ei, unsigned short* __restrict__ cnts)
{
  if (blockIdx.x < 5) {
    int m = blockIdx.x;           // 0..3 layers, 4 = skip_W
    const float* src = (m < 4) ? (Ws + (size_t)m * 16384) : skip_W;
    _Float16* oh = wth + (size_t)m * 16384;
    for (int i = threadIdx.x; i < 16384; i += 256){
      int c = i >> 7, k = i & 127;
      oh[i] = (_Float16)src[k * 128 + c];
    }
    return;
  }
  int blk = blockIdx.x - 5;
  __shared__ unsigned h[NBK];
  for (int i = threadIdx.x; i < NBK; i += 256) h[i] = 0;
  __syncthreads();
  int e0 = blk * 1024 + threadIdx.x;
#pragma unroll
  for (int i = 0; i < 4; ++i) {
    int e = e0 + i * 256;
    if (e < NITEM) {
      int d = (e < NE) ? ei[NE + e] : (e - NE);
      atomicAdd(&h[d >> 8], 1u);
    }
  }
  __syncthreads();
  for (int i = threadIdx.x; i < NBK; i += 256)
    cnts[(size_t)i * NBLK + blk] = (unsigned short)h[i];
}

__global__ __launch_bounds__(256) void k_scan1(const unsigned short* __restrict__ cnts,
    unsigned* __restrict__ offs, unsigned* __restrict__ totals)
{
  int b = blockIdx.x;
  int t = threadIdx.x;
  int lane = t & 63, wid = t >> 6;
  unsigned v[4];
  int i0 = t * 4;
#pragma unroll
  for (int k = 0; k < 4; ++k) {
    int i = i0 + k;
    v[k] = (i < NBLK) ? (unsigned)cnts[(size_t)b * NBLK + i] : 0u;
  }
  unsigned cs = v[0] + v[1] + v[2] + v[3];
  unsigned incl = cs;
#pragma unroll
  for (int o = 1; o < 64; o <<= 1) { unsigned u = __shfl_up(incl, o); if (lane >= o) incl += u; }
  __shared__ unsigned wsum[4];
  if (lane == 63) wsum[wid] = incl;
  __syncthreads();
  unsigned wbase = 0;
#pragma unroll
  for (int k = 0; k < 4; ++k) if (k < wid) wbase += wsum[k];
  unsigned run = wbase + incl - cs;
#pragma unroll
  for (int k = 0; k < 4; ++k) {
    int i = i0 + k;
    if (i < NBLK) offs[(size_t)b * NBLK + i] = run;
    run += v[k];
  }
  if (t == 255) totals[b] = wbase + incl;
}

__global__ __launch_bounds__(256) void k_scan2(const unsigned* __restrict__ totals, unsigned* __restrict__ base)
{
  int t = threadIdx.x;
  int lane = t & 63, wid = t >> 6;
  unsigned v = (t < NBK) ? totals[t] : 0u;
  unsigned incl = v;
#pragma unroll
  for (int o = 1; o < 64; o <<= 1) { unsigned u = __shfl_up(incl, o); if (lane >= o) incl += u; }
  __shared__ unsigned wsum[4];
  if (lane == 63) wsum[wid] = incl;
  __syncthreads();
  unsigned wbase = 0;
#pragma unroll
  for (int k = 0; k < 4; ++k) if (k < wid) wbase += wsum[k];
  if (t < NBK) base[t] = wbase + incl - v;
  if (t == 255) base[NBK] = wbase + incl;   // = NITEM
}

__global__ __launch_bounds__(256) void k_scatter(const int* __restrict__ ei, const unsigned* __restrict__ offs,
    const unsigned* __restrict__ base, unsigned* __restrict__ ebuf)
{
  int blk = blockIdx.x;
  __shared__ unsigned cur[NBK];
  for (int i = threadIdx.x; i < NBK; i += 256)
    cur[i] = base[i] + offs[(size_t)i * NBLK + blk];
  __syncthreads();
  int e0 = blk * 1024 + threadIdx.x;
#pragma unroll
  for (int i = 0; i < 4; ++i) {
    int e = e0 + i * 256;
    if (e < NITEM) {
      int s, d;
      if (e < NE) { s = ei[e]; d = ei[NE + e]; } else { s = e - NE; d = e - NE; }
      unsigned pos = atomicAdd(&cur[d >> 8], 1u);        // LDS atomic
      ebuf[pos] = ((unsigned)d << 16) | (unsigned)s;     // both < 65536
    }
  }
}

__global__ __launch_bounds__(256) void k_fine(const unsigned* __restrict__ ebuf, const unsigned* __restrict__ base,
    unsigned* __restrict__ starts, unsigned short* __restrict__ srcs, int N)
{
  int b = blockIdx.x;
  int t = threadIdx.x;
  unsigned lo = base[b], hi = base[b + 1];
  int d0 = b << 8;
  __shared__ unsigned h[256], st[256], wsum[4];
  h[t] = 0;
  __syncthreads();
  for (unsigned i = lo + t; i < hi; i += 256)
    atomicAdd(&h[(ebuf[i] >> 16) - d0], 1u);
  __syncthreads();
  unsigned v = h[t];
  int lane = t & 63, wid = t >> 6;
  unsigned incl = v;
#pragma unroll
  for (int o = 1; o < 64; o <<= 1) { unsigned u = __shfl_up(incl, o); if (lane >= o) incl += u; }
  if (lane == 63) wsum[wid] = incl;
  __syncthreads();
  unsigned wbase = 0;
#pragma unroll
  for (int k = 0; k < 4; ++k) if (k < wid) wbase += wsum[k];
  unsigned excl = wbase + incl - v;
  st[t] = excl;
  int dst = d0 + t;
  if (dst < N) starts[dst] = lo + excl;
  if (b == NBK - 1 && t == 0) starts[N] = hi;
  h[t] = 0;
  __syncthreads();
  for (unsigned i = lo + t; i < hi; i += 256) {
    unsigned w = ebuf[i];
    unsigned dl = (w >> 16) - d0;
    unsigned r = atomicAdd(&h[dl], 1u);
    srcs[lo + st[dl] + r] = (unsigned short)(w & 0xFFFFu);
  }
}

// ============ Round-6: LDS-staged weights for all GEMMs ============
// Round-5 rocprof: k_gemm2 53us with ALL pipes idle (Mfma 2%, VALU 4.5%, HBM 12%)
// -> latency-bound on 64 scattered L2 B-loads/wave at ~3 blocks/CU. Fix: stage the
// 32KB weight matrix in LDS (coalesced), XOR-swizzled (chunk c of row r stored at
// c^(r&7)) so ds_read_b128 of a B-fragment is bank-conflict-free (T2 pattern).

static __device__ __forceinline__ void stageB(const _Float16* __restrict__ wt,
                                              _Float16* __restrict__ sB, int tid)
{
  const half8* g = (const half8*)wt;
  half8* s = (half8*)sB;
#pragma unroll
  for (int it = 0; it < 8; ++it) {
    int idx = it * 256 + tid;            // 0..2047 chunk id (row 0..127, c 0..15)
    int row = idx >> 4, c = idx & 15;
    s[row * 16 + (c ^ (row & 7))] = g[idx];
  }
}

// fused skip+layer0 GEMM, two phases over one 32KB LDS buffer:
//   phase A: stage wt0, MFMA acc0 -> write hW + es/ed (acc0 dies)
//   phase B: stage wts, MFMA accs -> write skip
__global__ __launch_bounds__(256) void k_gemm2(const float* __restrict__ x,
    const _Float16* __restrict__ wt0, const _Float16* __restrict__ wts,
    const float* __restrict__ skip_b,
    const float* __restrict__ a_s, const float* __restrict__ a_d,
    float* __restrict__ skip, _Float16* __restrict__ hW,
    float* __restrict__ es, float* __restrict__ ed, int N)
{
  __shared__ _Float16 sB[128 * 128];     // 32 KB
  const half8* sBh = (const half8*)sB;
  int tid = threadIdx.x;
  int w  = tid >> 6;
  int l  = tid & 63;
  int ln = l & 15;
  int q  = l >> 4;
  int lx = ln & 7;                       // swizzle key
  int row0 = blockIdx.x * 64;
  int row = row0 + w * 16 + ln;
  bool rok = row < N;
  const float4* Arow = (const float4*)(x + (size_t)(rok ? row : 0) * 128);

  stageB(wt0, sB, tid);

  half8 af[4];
#pragma unroll
  for (int k32 = 0; k32 < 4; ++k32) {
    int f4 = k32 * 8 + q * 2;
    float4 a0 = make_float4(0.f,0.f,0.f,0.f), a1 = a0;
    if (rok) { a0 = Arow[f4]; a1 = Arow[f4 + 1]; }
    half8 h = {(_Float16)a0.x, (_Float16)a0.y, (_Float16)a0.z, (_Float16)a0.w,
               (_Float16)a1.x, (_Float16)a1.y, (_Float16)a1.z, (_Float16)a1.w};
    af[k32] = h;
  }
  __syncthreads();

  // ---- phase A: layer-0 ----
  {
    float4v acc[8];
#pragma unroll
    for (int t = 0; t < 8; ++t) acc[t] = (float4v){0,0,0,0};
#pragma unroll
    for (int k32 = 0; k32 < 4; ++k32) {
#pragma unroll
      for (int t = 0; t < 8; ++t) {
        half8 bv = sBh[(t * 16 + ln) * 16 + ((k32 * 4 + q) ^ lx)];
        acc[t] = __builtin_amdgcn_mfma_f32_16x16x32_f16(af[k32], bv, acc[t], 0, 0, 0);
      }
    }
#pragma unroll
    for (int t = 0; t < 8; ++t) {
#pragma unroll
      for (int r = 0; r < 4; ++r) {
        int gr = row0 + w * 16 + q * 4 + r;
        if (gr < N) hW[(size_t)gr * 128 + t * 16 + ln] = (_Float16)acc[t][r];
      }
    }
    float asv[8], adv[8];
#pragma unroll
    for (int t = 0; t < 8; ++t) { asv[t] = a_s[t * 16 + ln]; adv[t] = a_d[t * 16 + ln]; }
    float ps[4], pd[4];
#pragma unroll
    for (int r = 0; r < 4; ++r) {
      float s_ = 0.f, d_ = 0.f;
#pragma unroll
      for (int t = 0; t < 8; ++t) { s_ += acc[t][r] * asv[t]; d_ += acc[t][r] * adv[t]; }
      ps[r] = s_; pd[r] = d_;
    }
#pragma unroll
    for (int o = 1; o < 16; o <<= 1) {
#pragma unroll
      for (int r = 0; r < 4; ++r) { ps[r] += __shfl_xor(ps[r], o); pd[r] += __shfl_xor(pd[r], o); }
    }
    if (ln == 0) {
#pragma unroll
      for (int r = 0; r < 4; ++r) {
        int gr = row0 + w * 16 + q * 4 + r;
        if (gr < N) { es[gr] = ps[r]; ed[gr] = pd[r]; }
      }
    }
  }

  // ---- phase B: skip projection ----
  __syncthreads();                        // all reads of wt0 done
  stageB(wts, sB, tid);
  __syncthreads();
  {
    float4v acc[8];
#pragma unroll
    for (int t = 0; t < 8; ++t) acc[t] = (float4v){0,0,0,0};
#pragma unroll
    for (int k32 = 0; k32 < 4; ++k32) {
#pragma unroll
      for (int t = 0; t < 8; ++t) {
        half8 bv = sBh[(t * 16 + ln) * 16 + ((k32 * 4 + q) ^ lx)];
        acc[t] = __builtin_amdgcn_mfma_f32_16x16x32_f16(af[k32], bv, acc[t], 0, 0, 0);
      }
    }
    float bb[8];
#pragma unroll
    for (int t = 0; t < 8; ++t) bb[t] = skip_b[t * 16 + ln];
#pragma unroll
    for (int t = 0; t < 8; ++t) {
#pragma unroll
      for (int r = 0; r < 4; ++r) {
        int gr = row0 + w * 16 + q * 4 + r;
        if (gr < N) skip[(size_t)gr * 128 + t * 16 + ln] = acc[t][r] + bb[t];
      }
    }
  }
}

// layers 1-3 GEMM: fp16 A (hA mirror), LDS-staged B
__global__ __launch_bounds__(256) void gemm_h(const _Float16* __restrict__ A,
    const _Float16* __restrict__ wt,
    const float* __restrict__ a_s, const float* __restrict__ a_d,
    _Float16* __restrict__ outH, float* __restrict__ es, float* __restrict__ ed, int N)
{
  __shared__ _Float16 sB[128 * 128];     // 32 KB
  const half8* sBh = (const half8*)sB;
  int tid = threadIdx.x;
  int w  = tid >> 6;
  int l  = tid & 63;
  int ln = l & 15;
  int q  = l >> 6 == 0 ? (l >> 4) : (l >> 4);  // q = l>>4
  q = l >> 4;
  int lx = ln & 7;
  int row0 = blockIdx.x * 64;
  int row = row0 + w * 16 + ln;
  bool rok = row < N;
  const _Float16* Arow = A + (size_t)(rok ? row : 0) * 128;

  stageB(wt, sB, tid);

  half8 hz = {(_Float16)0,(_Float16)0,(_Float16)0,(_Float16)0,
              (_Float16)0,(_Float16)0,(_Float16)0,(_Float16)0};
  half8 af[4];
#pragma unroll
  for (int k32 = 0; k32 < 4; ++k32)
    af[k32] = rok ? *(const half8*)(Arow + k32 * 32 + q * 8) : hz;
  __syncthreads();

  float4v acc[8];
#pragma unroll
  for (int t = 0; t < 8; ++t) acc[t] = (float4v){0,0,0,0};
#pragma unroll
  for (int k32 = 0; k32 < 4; ++k32) {
#pragma unroll
    for (int t = 0; t < 8; ++t) {
      half8 bv = sBh[(t * 16 + ln) * 16 + ((k32 * 4 + q) ^ lx)];
      acc[t] = __builtin_amdgcn_mfma_f32_16x16x32_f16(af[k32], bv, acc[t], 0, 0, 0);
    }
  }

#pragma unroll
  for (int t = 0; t < 8; ++t) {
#pragma unroll
    for (int r = 0; r < 4; ++r) {
      int gr = row0 + w * 16 + q * 4 + r;
      if (gr < N) outH[(size_t)gr * 128 + t * 16 + ln] = (_Float16)acc[t][r];
    }
  }
  {
    float asv[8], adv[8];
#pragma unroll
    for (int t = 0; t < 8; ++t) { asv[t] = a_s[t * 16 + ln]; adv[t] = a_d[t * 16 + ln]; }
    float ps[4], pd[4];
#pragma unroll
    for (int r = 0; r < 4; ++r) {
      float s_ = 0.f, d_ = 0.f;
#pragma unroll
      for (int t = 0; t < 8; ++t) { s_ += acc[t][r] * asv[t]; d_ += acc[t][r] * adv[t]; }
      ps[r] = s_; pd[r] = d_;
    }
#pragma unroll
    for (int o = 1; o < 16; o <<= 1) {
#pragma unroll
      for (int r = 0; r < 4; ++r) { ps[r] += __shfl_xor(ps[r], o); pd[r] += __shfl_xor(pd[r], o); }
    }
    if (ln == 0) {
#pragma unroll
      for (int r = 0; r < 4; ++r) {
        int gr = row0 + w * 16 + q * 4 + r;
        if (gr < N) { es[gr] = ps[r]; ed[gr] = pd[r]; }
      }
    }
  }
}

// ---------------- fused edge softmax + aggregate + bias + LN + ELU + residual ----------------
// Round-4 (kept): dense CSR. Round-3 (kept): 64-lane epilogue, __expf ELU.
// Round-0 (kept): PF=4 preload. Round-5 (kept): fp16 mirror hA output.
__global__ __launch_bounds__(256) void edge_agg(
    const __half* __restrict__ hW, const float* __restrict__ es, const float* __restrict__ ed,
    const unsigned* __restrict__ starts, const unsigned short* __restrict__ srcs,
    const float* __restrict__ gb, const float* __restrict__ lg, const float* __restrict__ lb,
    const float* __restrict__ resid, float* __restrict__ hout, _Float16* __restrict__ hA,
    int do_elu, int N)
{
  __shared__ uint2 s_as[4][64];
  int wid = threadIdx.x >> 6;
  int lane = threadIdx.x & 63;
  int sub = lane >> 4;
  int sl  = lane & 15;
  int dst = blockIdx.x * 4 + wid;
  if (dst >= N) return;

  unsigned st0 = starts[dst];
  int deg = (int)(starts[dst + 1] - st0);
  float edv = ed[dst];

  float acc[8];
#pragma unroll
  for (int k = 0; k < 8; ++k) acc[k] = 0.f;
  const uint4* h4 = (const uint4*)hW;

  if (deg <= 64) {
    int s = 0;
    if (lane < deg) s = srcs[st0 + lane];
    const int PF = 4;
    uint4 qd_pre[PF];
#pragma unroll
    for (int i = 0; i < PF; ++i) {
      int idx = (i << 2) | sub;
      int sv = __shfl(s, idx);
      qd_pre[i] = make_uint4(0u, 0u, 0u, 0u);
      if (idx < deg) qd_pre[i] = h4[(size_t)sv * 16 + sl];
    }
    float x = -1e30f;
    if (lane < deg) {
      float xx = es[s] + edv;
      x = xx > 0.f ? xx : 0.2f * xx;
    }
    float m = x;
#pragma unroll
    for (int o = 32; o; o >>= 1) m = fmaxf(m, __shfl_xor(m, o));
    float p_ = (lane < deg) ? __expf(x - m) : 0.f;
    float z = p_;
#pragma unroll
    for (int o = 32; o; o >>= 1) z += __shfl_xor(z, o);
    float a_l = p_ / z;

    int iters = (deg + 3) >> 2;
#pragma unroll
    for (int i = 0; i < PF; ++i) {
      int idx = (i << 2) | sub;
      float a = __shfl(a_l, idx);
      uint4 qd = qd_pre[i];
      float2 f0 = __half22float2(*(__half2*)&qd.x);
      float2 f1 = __half22float2(*(__half2*)&qd.y);
      float2 f2 = __half22float2(*(__half2*)&qd.z);
      float2 f3 = __half22float2(*(__half2*)&qd.w);
      acc[0] += a * f0.x; acc[1] += a * f0.y;
      acc[2] += a * f1.x; acc[3] += a * f1.y;
      acc[4] += a * f2.x; acc[5] += a * f2.y;
      acc[6] += a * f3.x; acc[7] += a * f3.y;
    }
    for (int i = PF; i < iters; ++i) {
      int idx = (i << 2) | sub;
      float a = __shfl(a_l, idx);
      int sv = __shfl(s, idx);
      if (idx < deg) {
        uint4 qd = h4[(size_t)sv * 16 + sl];
        float2 f0 = __half22float2(*(__half2*)&qd.x);
        float2 f1 = __half22float2(*(__half2*)&qd.y);
        float2 f2 = __half22float2(*(__half2*)&qd.z);
        float2 f3 = __half22float2(*(__half2*)&qd.w);
        acc[0] += a * f0.x; acc[1] += a * f0.y;
        acc[2] += a * f1.x; acc[3] += a * f1.y;
        acc[4] += a * f2.x; acc[5] += a * f2.y;
        acc[6] += a * f3.x; acc[7] += a * f3.y;
      }
    }
  } else {
    float m = -1e30f;
    for (int j = lane; j < deg; j += 64) {
      float x = es[srcs[st0 + j]] + edv;
      x = x > 0.f ? x : 0.2f * x;
      m = fmaxf(m, x);
    }
#pragma unroll
    for (int o = 32; o; o >>= 1) m = fmaxf(m, __shfl_xor(m, o));
    float z = 0.f;
    for (int j = lane; j < deg; j += 64) {
      float x = es[srcs[st0 + j]] + edv;
      x = x > 0.f ? x : 0.2f * x;
      z += __expf(x - m);
    }
#pragma unroll
    for (int o = 32; o; o >>= 1) z += __shfl_xor(z, o);
    float inv_z = 1.0f / z;
    for (int c0 = 0; c0 < deg; c0 += 64) {
      int j = c0 + lane;
      int cnt = min(64, deg - c0);
      int s = 0; float p_ = 0.f;
      if (j < deg) {
        s = srcs[st0 + j];
        float x = es[s] + edv;
        x = x > 0.f ? x : 0.2f * x;
        p_ = __expf(x - m) * inv_z;
      }
      s_as[wid][lane] = make_uint2(__float_as_uint(p_), (unsigned)s);
      int iters = (cnt + 3) >> 2;
      for (int i = 0; i < iters; ++i) {
        int idx = (i << 2) | sub;
        bool valid = idx < cnt;
        uint2 av = s_as[wid][valid ? idx : 0];
        float a = valid ? __uint_as_float(av.x) : 0.f;
        uint4 qd = h4[(size_t)av.y * 16 + sl];
        float2 f0 = __half22float2(*(__half2*)&qd.x);
        float2 f1 = __half22float2(*(__half2*)&qd.y);
        float2 f2 = __half22float2(*(__half2*)&qd.z);
        float2 f3 = __half22float2(*(__half2*)&qd.w);
        acc[0] += a * f0.x; acc[1] += a * f0.y;
        acc[2] += a * f1.x; acc[3] += a * f1.y;
        acc[4] += a * f2.x; acc[5] += a * f2.y;
        acc[6] += a * f3.x; acc[7] += a * f3.y;
      }
    }
  }

#pragma unroll
  for (int k = 0; k < 8; ++k) {
    acc[k] += __shfl_xor(acc[k], 16);
    acc[k] += __shfl_xor(acc[k], 32);
  }

  float4 g0 = ((const float4*)gb)[sl * 2];
  float4 g1 = ((const float4*)gb)[sl * 2 + 1];
  float v[8];
  v[0] = acc[0] + g0.x; v[1] = acc[1] + g0.y; v[2] = acc[2] + g0.z; v[3] = acc[3] + g0.w;
  v[4] = acc[4] + g1.x; v[5] = acc[5] + g1.y; v[6] = acc[6] + g1.z; v[7] = acc[7] + g1.w;
  float s1 = 0.f, s2 = 0.f;
#pragma unroll
  for (int k = 0; k < 8; ++k) { s1 += v[k]; s2 += v[k] * v[k]; }
#pragma unroll
  for (int o = 8; o; o >>= 1) { s1 += __shfl_xor(s1, o); s2 += __shfl_xor(s2, o); }
  float mu = s1 * (1.f / 128.f);
  float var = s2 * (1.f / 128.f) - mu * mu;
  float rstd = rsqrtf(var + 1e-5f);

  float va = sub == 0 ? v[0] : (sub == 1 ? v[2] : (sub == 2 ? v[4] : v[6]));
  float vb = sub == 0 ? v[1] : (sub == 1 ? v[3] : (sub == 2 ? v[5] : v[7]));
  int col = sl * 8 + sub * 2;
  float2 Lv = *(const float2*)(lg + col);
  float2 Bv = *(const float2*)(lb + col);
  float2 Rv = *(const float2*)(resid + (long)dst * 128 + col);
  float t0 = (va - mu) * rstd * Lv.x + Bv.x;
  float t1 = (vb - mu) * rstd * Lv.y + Bv.y;
  if (do_elu) {
    t0 = t0 > 0.f ? t0 : __expf(t0) - 1.f;
    t1 = t1 > 0.f ? t1 : __expf(t1) - 1.f;
  }
  float y0 = t0 + Rv.x, y1 = t1 + Rv.y;
  *(float2*)(hout + (long)dst * 128 + col) = make_float2(y0, y1);
  if (hA) {
    half2v hv = {(_Float16)y0, (_Float16)y1};
    *(half2v*)(hA + (long)dst * 128 + col) = hv;
  }
}

// ---------------- pooling (mean + max per graph) ----------------
__global__ __launch_bounds__(128) void k_pool(const float* __restrict__ h, const int* __restrict__ batch,
    float* __restrict__ gsum, unsigned* __restrict__ gmax, int* __restrict__ gcnt, int N)
{
  int n0 = blockIdx.x * 64;
  int c = threadIdx.x;
  int cur = -1; float ls = 0.f, lm = -1e30f; int lc = 0;
  for (int i = 0; i < 64; ++i) {
    int n = n0 + i;
    if (n >= N) break;
    int g = batch[n];
    if (g != cur) {
      if (lc > 0) {
        atomicAdd(&gsum[cur * HID + c], ls);
        atomicMax(&gmax[cur * HID + c], fenc(lm));
        if (c == 0) atomicAdd(&gcnt[cur], lc);
      }
      cur = g; ls = 0.f; lm = -1e30f; lc = 0;
    }
    float v = h[(long)n * HID + c];
    ls += v; lm = fmaxf(lm, v); lc++;
  }
  if (lc > 0) {
    atomicAdd(&gsum[cur * HID + c], ls);
    atomicMax(&gmax[cur * HID + c], fenc(lm));
    if (c == 0) atomicAdd(&gcnt[cur], lc);
  }
}

// ---------------- final MLP: one block per graph ----------------
__global__ __launch_bounds__(128) void k_mlp(const float* __restrict__ gsum,
    const unsigned* __restrict__ gmax, const int* __restrict__ gcnt,
    const float* __restrict__ W1, const float* __restrict__ b1,
    const float* __restrict__ W2, const float* __restrict__ b2,
    const float* __restrict__ W3, const float* __restrict__ b3,
    float* __restrict__ out)
{
  int g = blockIdx.x;
  int c = threadIdx.x;
  __shared__ float G[256];
  __shared__ float O1[128];
  __shared__ float O2[64];
  float inv = 1.0f / fmaxf((float)gcnt[g], 1.0f);
  G[c]       = gsum[g * HID + c] * inv;
  G[128 + c] = fdec(gmax[g * HID + c]);
  __syncthreads();
  {
    float acc = 0.f;
#pragma unroll 8
    for (int k = 0; k < 256; ++k) acc += G[k] * W1[k * 128 + c];
    float v = acc + b1[c];
    O1[c] = v > 0.f ? v : 0.f;
  }
  __syncthreads();
  if (c < 64) {
    float acc = 0.f;
#pragma unroll 8
    for (int k = 0; k < 128; ++k) acc += O1[k] * W2[k * 64 + c];
    float v = acc + b2[c];
    O2[c] = v > 0.f ? v : 0.f;
  }
  __syncthreads();
  if (c < 4) {
    float acc = 0.f;
#pragma unroll 8
    for (int k = 0; k < 64; ++k) acc += O2[k] * W3[k * 4 + c];
    out[g * 4 + c] = acc + b3[c];
  }
}

extern "C" void kernel_launch(void* const* d_in, const int* in_sizes, int n_in,
                              void* d_out, int out_size, void* d_ws, size_t ws_size,
                              hipStream_t stream) {
  const float* x      = (const float*)d_in[0];
  const int*   ei     = (const int*)d_in[1];
  const int*   batch  = (const int*)d_in[2];
  const float* Ws     = (const float*)d_in[3];
  const float* a_src  = (const float*)d_in[4];
  const float* a_dst  = (const float*)d_in[5];
  const float* gat_b  = (const float*)d_in[6];
  const float* ln_g   = (const float*)d_in[7];
  const float* ln_b   = (const float*)d_in[8];
  const float* skip_W = (const float*)d_in[9];
  const float* skip_b = (const float*)d_in[10];
  const float* W1     = (const float*)d_in[11];
  const float* b1     = (const float*)d_in[12];
  const float* W2     = (const float*)d_in[13];
  const float* b2     = (const float*)d_in[14];
  const float* W3     = (const float*)d_in[15];
  const float* b3     = (const float*)d_in[16];
  float* out = (float*)d_out;

  const int N = NND;

  char* p = (char*)d_ws;
  auto alloc = [&](size_t bytes) -> void* {
    void* r = (void*)p;
    p += (bytes + 255) & ~(size_t)255;
    return r;
  };
  float*  skip  = (float*)alloc(sizeof(float) * (size_t)N * HID);
  float*  hcur  = (float*)alloc(sizeof(float) * (size_t)N * HID);
  _Float16* hW  = (_Float16*)alloc(sizeof(_Float16) * (size_t)N * HID);
  _Float16* hA  = (_Float16*)alloc(sizeof(_Float16) * (size_t)N * HID);
  float*  es    = (float*)alloc(sizeof(float) * N);
  float*  ed    = (float*)alloc(sizeof(float) * N);
  _Float16* wth = (_Float16*)alloc(sizeof(_Float16) * 5 * 16384);
  unsigned short* cnts = (unsigned short*)alloc(sizeof(unsigned short) * (size_t)NBK * NBLK);
  unsigned* offs   = (unsigned*)alloc(sizeof(unsigned) * (size_t)NBK * NBLK);
  unsigned* totals = (unsigned*)alloc(sizeof(unsigned) * NBK);
  unsigned* base   = (unsigned*)alloc(sizeof(unsigned) * (NBK + 1));
  unsigned* ebuf   = (unsigned*)alloc(sizeof(unsigned) * (size_t)NITEM);
  unsigned* starts = (unsigned*)alloc(sizeof(unsigned) * (N + 1));
  unsigned short* srcs = (unsigned short*)alloc(sizeof(unsigned short) * (size_t)NITEM);
  char*   zbeg  = p;
  float*  gsum  = (float*)alloc(sizeof(float) * NGR * HID);
  unsigned* gmax = (unsigned*)alloc(sizeof(unsigned) * NGR * HID);
  int*    gcnt  = (int*)alloc(sizeof(int) * NGR);
  size_t zlen = (size_t)(p - zbeg);

  int gblocks = (N + 63) / 64;            // 782

  // ---- CSR build (atomic-free counting sort) ∪ weight convert ----
  k_count  <<<5 + NBLK, 256, 0, stream>>>(Ws, skip_W, wth, ei, cnts);
  k_scan1  <<<NBK, 256, 0, stream>>>(cnts, offs, totals);
  k_scan2  <<<1, 256, 0, stream>>>(totals, base);
  k_scatter<<<NBLK, 256, 0, stream>>>(ei, offs, base, ebuf);
  k_fine   <<<NBK, 256, 0, stream>>>(ebuf, base, starts, srcs, N);

  // ---- fused skip + layer-0 GEMM (LDS-staged weights, 2 phases) ----
  k_gemm2<<<gblocks, 256, 0, stream>>>(x, wth, wth + 4 * 16384, skip_b, a_src, a_dst,
                                       skip, hW, es, ed, N);
  edge_agg<<<(N + 3) / 4, 256, 0, stream>>>((const __half*)hW, es, ed, starts, srcs,
                                 gat_b, ln_g, ln_b, skip, hcur, hA, 1, N);

  // ---- layers 1..3 (fp16 A path, LDS-staged weights) ----
  for (int l = 1; l < NLAYER; ++l) {
    gemm_h<<<gblocks, 256, 0, stream>>>(hA, wth + (size_t)l * 16384,
                                        a_src + l * HID, a_dst + l * HID,
                                        hW, es, ed, N);
    edge_agg<<<(N + 3) / 4, 256, 0, stream>>>((const __half*)hW, es, ed, starts, srcs,
                                   gat_b + l * HID, ln_g + l * HID, ln_b + l * HID,
                                   hcur, hcur, (l < NLAYER - 1) ? hA : (_Float16*)nullptr,
                                   (l < NLAYER - 1) ? 1 : 0, N);
  }

  // ---- pooling + MLP ----
  hipMemsetAsync(zbeg, 0, zlen, stream);
  k_pool<<<(N + 63) / 64, 128, 0, stream>>>(hcur, batch, gsum, gmax, gcnt, N);
  k_mlp<<<NGR, 128, 0, stream>>>(gsum, gmax, gcnt, W1, b1, W2, b2, W3, b3, out);
}